// Round 8
// baseline (591.214 us; speedup 1.0000x reference)
//
#include <hip/hip_runtime.h>
#include <hip/hip_cooperative_groups.h>

namespace cg = cooperative_groups;

#define N_NODES 50000
#define N_EDGES 800000
#define DIM 64
#define NEG_SLOPE 0.2f
#define NEG_INF (-__builtin_inff())
#define NB      3125         // phase-1 units: 16 GEMM rows + 256 edges each
#define NBIN    782          // coarse bins: bin = dst>>6 (64 nodes/bin)
#define SEGS    8            // per-bin segments keyed by REAL XCC_ID
#define SEGCAP  256          // per (seg,bin) capacity: mean 128, +11 sigma
#define LMAX    64           // per-node list cap (Poisson 16: P(>=64)~1e-19)
#define GRID    1024         // 4 blocks/CU — wide margin for coop validator (LDS allows 7)

typedef _Float16 half8 __attribute__((ext_vector_type(8)));

// ---------------- fused cooperative kernel (phases 0/1/2) ----------------
// Round-7 lesson: hipLaunchCooperativeKernel's return was ignored; absmax
// 5.28 == max|ref| -> output was memset-zero -> the launch never ran.
// This round: smaller grid (1024), explicit seq_cst agent fences on BOTH
// sides of each grid sync (release writeback / acquire invalidate across
// non-coherent XCD L2s), and a host-side fallback to the proven r5 path if
// the cooperative launch is rejected.
__global__ __launch_bounds__(256, 4) void k_fused(
    const float* __restrict__ x,
    const float* __restrict__ W,
    const float* __restrict__ b_msg,
    const float* __restrict__ b_edge,
    _Float16* __restrict__ xmh,
    const int* __restrict__ eidx,
    const float* __restrict__ eattr,
    unsigned* __restrict__ tails,
    int2* __restrict__ rec,
    const float4* __restrict__ W_edge4,
    const float4* __restrict__ att4,
    const float4* __restrict__ x4,
    float4* __restrict__ out4)
{
    __shared__ union {
        struct { float Ws[DIM * DIM]; float xs[16 * DIM]; } pre;       // 20 KB
        struct { int2 lst[32 * LMAX]; unsigned degs[32]; unsigned scnt[SEGS]; } agg; // 16.2 KB
    } sm;
    cg::grid_group gg = cg::this_grid();
    int tid = threadIdx.x;
    int bid = blockIdx.x;

    // ---- phase 0: zero tail counters ----
    {
        int t0 = bid * 256 + tid;
        if (t0 < SEGS * NBIN) tails[t0] = 0;
    }
    __threadfence();                            // release: flush dirty lines
    gg.sync();
    __threadfence();                            // acquire: invalidate stale lines

    // ---- phase 1: GEMM + XCD-keyed partition (grid-strided) ----
    unsigned xcc;
    asm volatile("s_getreg_b32 %0, hwreg(HW_REG_XCC_ID, 0, 4)" : "=s"(xcc));
    int seg = (int)(xcc & 7u);                  // real XCD id, wave-uniform

    const float4* W4 = (const float4*)W;
    float4* Ws4 = (float4*)sm.pre.Ws;
    #pragma unroll
    for (int i = 0; i < 4; ++i) Ws4[tid + 256 * i] = W4[tid + 256 * i];

    int w = tid >> 6;                 // wave -> rows 4w..4w+3 of the unit
    int d = tid & 63;
    float bias = b_msg[d] + b_edge[d];

    for (int u = bid; u < NB; u += GRID) {
        int e = u * 256 + tid;                  // 3125*256 == N_EDGES exactly
        int    edst = eidx[N_EDGES + e];
        int    esrc = eidx[e];
        float  ea   = eattr[e];
        int bin = edst >> 6;
        unsigned slot = atomicAdd(tails + (seg * NBIN + bin), 1u);

        __syncthreads();                        // prev iter's xs readers done
        ((float4*)sm.pre.xs)[tid] =
            ((const float4*)(x + (size_t)u * 16 * DIM))[tid];
        __syncthreads();                        // xs (and Ws, iter 0) visible

        if (slot < SEGCAP)                      // tail-packed into XCD's slab
            rec[(size_t)(seg * NBIN + bin) * SEGCAP + slot] =
                make_int2((esrc << 6) | (edst & 63), __float_as_int(ea));

        float s0 = bias, s1 = bias, s2 = bias, s3 = bias;
        const float* xr = sm.pre.xs + (w * 4) * DIM;
        #pragma unroll
        for (int k = 0; k < DIM; ++k) {
            float wv = sm.pre.Ws[k * DIM + d];
            s0 = fmaf(xr[k], wv, s0);
            s1 = fmaf(xr[DIM + k], wv, s1);
            s2 = fmaf(xr[2 * DIM + k], wv, s2);
            s3 = fmaf(xr[3 * DIM + k], wv, s3);
        }
        _Float16* o = xmh + ((size_t)u * 16 + w * 4) * DIM + d;
        o[0] = (_Float16)s0;
        o[DIM] = (_Float16)s1;
        o[2 * DIM] = (_Float16)s2;
        o[3 * DIM] = (_Float16)s3;
    }

    __threadfence();                            // release rec/tails/xmh
    gg.sync();
    __threadfence();                            // acquire on reader side

    // ---- phase 2: per-half-bin aggregation (grid-strided) ----
    int lane = tid & 63;
    int wvi  = tid >> 6;
    int g = lane >> 3, t = lane & 7;
    int rr = wvi * 8 + g;                       // this group's node slot (0..31)

    float4 wa = W_edge4[2 * t], wb = W_edge4[2 * t + 1];
    float4 aa = att4[2 * t],    ab = att4[2 * t + 1];
    float we[8] = {wa.x, wa.y, wa.z, wa.w, wb.x, wb.y, wb.z, wb.w};
    float at[8] = {aa.x, aa.y, aa.z, aa.w, ab.x, ab.y, ab.z, ab.w};

    for (int u = bid; u < NBIN * 2; u += GRID) {
        int bin  = u >> 1;
        int half = u & 1;
        __syncthreads();                        // LDS reuse (phase 1 / prev iter)
        if (tid < SEGS) {
            unsigned c = tails[tid * NBIN + bin];
            sm.agg.scnt[tid] = c > SEGCAP ? SEGCAP : c;
        }
        if (tid < 32) sm.agg.degs[tid] = 0;
        __syncthreads();

        for (int s = 0; s < SEGS * SEGCAP; s += 256) {
            int slot = s + tid;
            int sg = slot >> 8, i = slot & 255;
            if ((unsigned)i < sm.agg.scnt[sg]) {
                int2 r = rec[(size_t)(sg * NBIN + bin) * SEGCAP + i];
                unsigned nr = (unsigned)r.x & 63u;
                if ((int)(nr >> 5) == half) {
                    unsigned k = atomicAdd(&sm.agg.degs[nr & 31u], 1u);
                    if (k < LMAX) sm.agg.lst[(nr & 31u) * LMAX + k] = r;
                }
            }
        }
        __syncthreads();

        int node = bin * 64 + half * 32 + rr;
        if (node < N_NODES) {
            unsigned deg = sm.agg.degs[rr];
            if (deg > LMAX) deg = LMAX;
            size_t obase = (size_t)node * 16 + 2 * t;
            if (deg == 0) {
                out4[obase] = x4[obase];
                out4[obase + 1] = x4[obase + 1];
            } else {
                const int2* L = sm.agg.lst + rr * LMAX;
                int2 r = L[0];
                float ea = __int_as_float(r.y);
                half8 h  = ((const half8*)xmh)[(size_t)((unsigned)r.x >> 6) * 8 + t];

                float m = NEG_INF, denom = 0.f;
                float v[8];
                #pragma unroll
                for (int k = 0; k < 8; ++k) v[k] = 0.f;

                unsigned i = 0;
                while (true) {
                    bool more = (i + 1) < deg;  // group-uniform
                    float ea2; half8 h2;
                    if (more) {
                        int2 r2 = L[i + 1];
                        ea2 = __int_as_float(r2.y);
                        h2  = ((const half8*)xmh)[(size_t)((unsigned)r2.x >> 6) * 8 + t];
                    }
                    float msg[8];
                    float p = 0.f;
                    #pragma unroll
                    for (int k = 0; k < 8; ++k) {
                        float f = (float)h[k];
                        msg[k] = fmaf(ea, we[k], f);
                        float lr = fmaxf(msg[k], NEG_SLOPE * msg[k]); // leaky
                        p = fmaf(lr, at[k], p);
                    }
                    p += __shfl_xor(p, 1, 64);
                    p += __shfl_xor(p, 2, 64);
                    p += __shfl_xor(p, 4, 64);  // group-uniform logit
                    if (i == 0) {
                        m = p; denom = 1.f;
                        #pragma unroll
                        for (int k = 0; k < 8; ++k) v[k] = msg[k];
                    } else {
                        float M  = fmaxf(m, p);
                        float so = __expf(m - M);
                        float sn = __expf(p - M);
                        denom = fmaf(denom, so, sn);
                        #pragma unroll
                        for (int k = 0; k < 8; ++k)
                            v[k] = fmaxf(v[k] * so, msg[k] * sn);
                        m = M;
                    }
                    if (!more) break;
                    ea = ea2; h = h2; ++i;
                }
                float inv = 1.0f / (denom + 1e-16f);
                float4 xa = x4[obase], xb = x4[obase + 1];
                float4 r0, r1;
                r0.x = fmaf(v[0], inv, xa.x);
                r0.y = fmaf(v[1], inv, xa.y);
                r0.z = fmaf(v[2], inv, xa.z);
                r0.w = fmaf(v[3], inv, xa.w);
                r1.x = fmaf(v[4], inv, xb.x);
                r1.y = fmaf(v[5], inv, xb.y);
                r1.z = fmaf(v[6], inv, xb.z);
                r1.w = fmaf(v[7], inv, xb.w);
                out4[obase] = r0;
                out4[obase + 1] = r1;
            }
        }
    }
}

// ---------------- fallback path: r5 kernels verbatim (known-good) ----------
__global__ __launch_bounds__(256) void k_pre(const float* __restrict__ x,
                                             const float* __restrict__ W,
                                             const float* __restrict__ b_msg,
                                             const float* __restrict__ b_edge,
                                             _Float16* __restrict__ xmh,
                                             const int* __restrict__ eidx,
                                             const float* __restrict__ eattr,
                                             unsigned* __restrict__ tails,
                                             int2* __restrict__ rec) {
    __shared__ float Ws[DIM * DIM];
    __shared__ float xs[16 * DIM];
    int tid = threadIdx.x;
    int bid = blockIdx.x;

    int e = bid * 256 + tid;
    int    edst = eidx[N_EDGES + e];
    int    esrc = eidx[e];
    float  ea   = eattr[e];
    unsigned xcc;
    asm volatile("s_getreg_b32 %0, hwreg(HW_REG_XCC_ID, 0, 4)" : "=s"(xcc));
    int seg = (int)(xcc & 7u);
    int bin = edst >> 6;
    unsigned slot = atomicAdd(tails + (seg * NBIN + bin), 1u);

    const float4* W4 = (const float4*)W;
    float4* Ws4 = (float4*)Ws;
    #pragma unroll
    for (int i = 0; i < 4; ++i) Ws4[tid + 256 * i] = W4[tid + 256 * i];
    int base = bid * 16;
    ((float4*)xs)[tid] = ((const float4*)(x + (size_t)base * DIM))[tid];
    __syncthreads();

    if (slot < SEGCAP)
        rec[(size_t)(seg * NBIN + bin) * SEGCAP + slot] =
            make_int2((esrc << 6) | (edst & 63), __float_as_int(ea));

    int w = tid >> 6;
    int d = tid & 63;
    float bias = b_msg[d] + b_edge[d];
    float s0 = bias, s1 = bias, s2 = bias, s3 = bias;
    const float* xr = xs + (w * 4) * DIM;
    #pragma unroll
    for (int k = 0; k < DIM; ++k) {
        float wv = Ws[k * DIM + d];
        s0 = fmaf(xr[k], wv, s0);
        s1 = fmaf(xr[DIM + k], wv, s1);
        s2 = fmaf(xr[2 * DIM + k], wv, s2);
        s3 = fmaf(xr[3 * DIM + k], wv, s3);
    }
    _Float16* o = xmh + ((size_t)base + w * 4) * DIM + d;
    o[0] = (_Float16)s0;
    o[DIM] = (_Float16)s1;
    o[2 * DIM] = (_Float16)s2;
    o[3 * DIM] = (_Float16)s3;
}

__global__ __launch_bounds__(256) void k_aggregate(const half8* __restrict__ xm8,
                                                   const int2* __restrict__ rec,
                                                   const unsigned* __restrict__ tails,
                                                   const float4* __restrict__ W_edge4,
                                                   const float4* __restrict__ att4,
                                                   const float4* __restrict__ x4,
                                                   float4* __restrict__ out4) {
    __shared__ int2 lst[32 * LMAX];
    __shared__ unsigned degs[32];
    __shared__ unsigned scnt[SEGS];
    int tid  = threadIdx.x;
    int bin  = blockIdx.x >> 1;
    int half = blockIdx.x & 1;

    if (tid < SEGS) {
        unsigned c = tails[tid * NBIN + bin];
        scnt[tid] = c > SEGCAP ? SEGCAP : c;
    }
    if (tid < 32) degs[tid] = 0;
    __syncthreads();

    for (int s = 0; s < SEGS * SEGCAP; s += 256) {
        int slot = s + tid;
        int sg = slot >> 8, i = slot & 255;
        if ((unsigned)i < scnt[sg]) {
            int2 r = rec[(size_t)(sg * NBIN + bin) * SEGCAP + i];
            unsigned nr = (unsigned)r.x & 63u;
            if ((int)(nr >> 5) == half) {
                unsigned k = atomicAdd(&degs[nr & 31u], 1u);
                if (k < LMAX) lst[(nr & 31u) * LMAX + k] = r;
            }
        }
    }
    __syncthreads();

    int lane = tid & 63;
    int wvi  = tid >> 6;
    int g = lane >> 3, t = lane & 7;
    int rr = wvi * 8 + g;
    int node = bin * 64 + half * 32 + rr;
    if (node >= N_NODES) return;

    unsigned deg = degs[rr];
    if (deg > LMAX) deg = LMAX;
    size_t obase = (size_t)node * 16 + 2 * t;
    if (deg == 0) {
        out4[obase] = x4[obase];
        out4[obase + 1] = x4[obase + 1];
        return;
    }
    float4 wa = W_edge4[2 * t], wb = W_edge4[2 * t + 1];
    float4 aa = att4[2 * t],    ab = att4[2 * t + 1];
    float we[8] = {wa.x, wa.y, wa.z, wa.w, wb.x, wb.y, wb.z, wb.w};
    float at[8] = {aa.x, aa.y, aa.z, aa.w, ab.x, ab.y, ab.z, ab.w};

    const int2* L = lst + rr * LMAX;
    int2 r = L[0];
    float ea = __int_as_float(r.y);
    half8 h  = xm8[(size_t)((unsigned)r.x >> 6) * 8 + t];

    float m = NEG_INF, denom = 0.f;
    float v[8];
    #pragma unroll
    for (int k = 0; k < 8; ++k) v[k] = 0.f;

    unsigned i = 0;
    while (true) {
        bool more = (i + 1) < deg;
        float ea2; half8 h2;
        if (more) {
            int2 r2 = L[i + 1];
            ea2 = __int_as_float(r2.y);
            h2  = xm8[(size_t)((unsigned)r2.x >> 6) * 8 + t];
        }
        float msg[8];
        float p = 0.f;
        #pragma unroll
        for (int k = 0; k < 8; ++k) {
            float f = (float)h[k];
            msg[k] = fmaf(ea, we[k], f);
            float lr = fmaxf(msg[k], NEG_SLOPE * msg[k]);
            p = fmaf(lr, at[k], p);
        }
        p += __shfl_xor(p, 1, 64);
        p += __shfl_xor(p, 2, 64);
        p += __shfl_xor(p, 4, 64);
        if (i == 0) {
            m = p; denom = 1.f;
            #pragma unroll
            for (int k = 0; k < 8; ++k) v[k] = msg[k];
        } else {
            float M  = fmaxf(m, p);
            float so = __expf(m - M);
            float sn = __expf(p - M);
            denom = fmaf(denom, so, sn);
            #pragma unroll
            for (int k = 0; k < 8; ++k)
                v[k] = fmaxf(v[k] * so, msg[k] * sn);
            m = M;
        }
        if (!more) break;
        ea = ea2; h = h2; ++i;
    }
    float inv = 1.0f / (denom + 1e-16f);
    float4 xa = x4[obase], xb = x4[obase + 1];
    float4 r0, r1;
    r0.x = fmaf(v[0], inv, xa.x);
    r0.y = fmaf(v[1], inv, xa.y);
    r0.z = fmaf(v[2], inv, xa.z);
    r0.w = fmaf(v[3], inv, xa.w);
    r1.x = fmaf(v[4], inv, xb.x);
    r1.y = fmaf(v[5], inv, xb.y);
    r1.z = fmaf(v[6], inv, xb.z);
    r1.w = fmaf(v[7], inv, xb.w);
    out4[obase] = r0;
    out4[obase + 1] = r1;
}

extern "C" void kernel_launch(void* const* d_in, const int* in_sizes, int n_in,
                              void* d_out, int out_size, void* d_ws, size_t ws_size,
                              hipStream_t stream) {
    const float* x      = (const float*)d_in[0];
    const int*   eidx   = (const int*)d_in[1];     // [2, E] int32
    const float* eattr  = (const float*)d_in[2];
    const float* W_msg  = (const float*)d_in[3];
    const float* b_msg  = (const float*)d_in[4];
    const float* W_edge = (const float*)d_in[5];   // [1, D]
    const float* b_edge = (const float*)d_in[6];
    const float* att    = (const float*)d_in[7];
    float* out = (float*)d_out;

    _Float16* xmh   = (_Float16*)d_ws;
    int2*     rec   = (int2*)(xmh + (size_t)N_NODES * DIM);
    unsigned* tails = (unsigned*)(rec + (size_t)SEGS * NBIN * SEGCAP);

    const float4* W_edge4 = (const float4*)W_edge;
    const float4* att4    = (const float4*)att;
    const float4* x4      = (const float4*)x;
    float4*       out4    = (float4*)out;

    void* args[] = {
        (void*)&x, (void*)&W_msg, (void*)&b_msg, (void*)&b_edge,
        (void*)&xmh, (void*)&eidx, (void*)&eattr, (void*)&tails,
        (void*)&rec, (void*)&W_edge4, (void*)&att4, (void*)&x4, (void*)&out4
    };
    hipError_t rc = hipLaunchCooperativeKernel((const void*)k_fused,
                                               dim3(GRID), dim3(256),
                                               args, 0, stream);
    if (rc != hipSuccess) {
        // fallback: proven r5 three-dispatch pipeline
        (void)hipMemsetAsync(tails, 0, (size_t)SEGS * NBIN * 4, stream);
        k_pre<<<NB, 256, 0, stream>>>(x, W_msg, b_msg, b_edge, xmh,
                                      eidx, eattr, tails, rec);
        k_aggregate<<<NBIN * 2, 256, 0, stream>>>(
            (const half8*)xmh, rec, tails, W_edge4, att4, x4, out4);
    }
}

// Round 9
// 125.521 us; speedup vs baseline: 4.7101x; 4.7101x over previous
//
#include <hip/hip_runtime.h>

#define N_NODES 50000
#define N_EDGES 800000
#define DIM 64
#define NEG_SLOPE 0.2f
#define NEG_INF (-__builtin_inff())
#define NB      3125         // GEMM units: 16 rows each (exact)
#define NBIN    782          // coarse bins: bin = dst>>6 (64 nodes/bin)
#define SEGS    8            // per-bin segments keyed by REAL XCC_ID
#define SEGCAP  384          // per (seg,bin) capacity (mean 128; wide margin for
                             // heavy-block->XCD imbalance; overflow drops as before)
#define LMAX    64           // per-node list cap (Poisson 16: P(>=64)~1e-19)
#define HB      196          // heavy blocks: 196*4096 >= 800000
#define EPB     4096         // edges per heavy block (16 per thread)

typedef _Float16 half8 __attribute__((ext_vector_type(8)));

// K1: all 3125 blocks do 16 GEMM rows; the first 196 ("heavy") also partition
// 4096 edges each via a block-local LDS histogram.
// Round-8 theory: k_pre was pinned at 46-58 us across 57->32 MB write traffic
// because it is DEVICE-ATOMIC-BOUND: 800K fabric atomicAdds / 46 us ~= 7
// atomics/cycle, a plausible issue ceiling. This round cuts global atomics to
// ~150K (one per non-empty bin per heavy block, ranks from LDS atomics), with
// the GEMM compute hiding the reservation latency; records then write to
// base+rank -> consecutive slots -> genuine line packing as a bonus.
__global__ __launch_bounds__(256) void k_pre(const float* __restrict__ x,
                                             const float* __restrict__ W,
                                             const float* __restrict__ b_msg,
                                             const float* __restrict__ b_edge,
                                             _Float16* __restrict__ xmh,
                                             const int* __restrict__ eidx,
                                             const float* __restrict__ eattr,
                                             unsigned* __restrict__ tails,
                                             int2* __restrict__ rec) {
    __shared__ float Ws[DIM * DIM];   // 16 KB
    __shared__ float xs[16 * DIM];    // 4 KB
    __shared__ unsigned hb[NBIN];     // 3.1 KB: histogram, then base, in place
    int tid = threadIdx.x;
    int bid = blockIdx.x;
    bool heavy = bid < HB;            // block-uniform

    unsigned xcc;
    asm volatile("s_getreg_b32 %0, hwreg(HW_REG_XCC_ID, 0, 4)" : "=s"(xcc));
    int seg = (int)(xcc & 7u);        // real XCD id

    if (heavy)
        for (int b = tid; b < NBIN; b += 256) hb[b] = 0;

    const float4* W4 = (const float4*)W;
    float4* Ws4 = (float4*)Ws;
    #pragma unroll
    for (int i = 0; i < 4; ++i) Ws4[tid + 256 * i] = W4[tid + 256 * i];
    int base = bid * 16;              // 3125*16 == N_NODES exactly
    ((float4*)xs)[tid] = ((const float4*)(x + (size_t)base * DIM))[tid];
    __syncthreads();                  // xs/Ws staged; hb zeroed

    // ---- pass A (heavy): rank edges in block-local LDS histogram ----
    // pack: rank(12b) | bin(10b) | dst&63(6b); sentinel = all-ones (bin field
    // 0x3FF > 781 is impossible for valid entries)
    unsigned rl[16];
    if (heavy) {
        int ebase = bid * EPB;
        #pragma unroll
        for (int j = 0; j < 16; ++j) {
            int e = ebase + j * 256 + tid;      // coalesced 1KB per iteration
            rl[j] = 0xFFFFFFFFu;
            if (e < N_EDGES) {
                int edst = eidx[N_EDGES + e];
                unsigned bin = (unsigned)edst >> 6;
                unsigned r = atomicAdd(&hb[bin], 1u);   // LDS atomic: cheap
                rl[j] = r | (bin << 12) | ((unsigned)(edst & 63) << 22);
            }
        }
    }
    __syncthreads();                  // histogram complete

    // ---- pass B (heavy): ONE global atomic per non-empty bin ----
    if (heavy) {
        for (int b = tid; b < NBIN; b += 256) {
            unsigned h = hb[b];
            if (h) hb[b] = atomicAdd(tails + (seg * NBIN + b), h); // base
        }
    }

    // ---- GEMM (all blocks) — hides pass-B atomic latency ----
    int w = tid >> 6;                 // wave -> rows base+4w..+3
    int d = tid & 63;
    float bias = b_msg[d] + b_edge[d];
    float s0 = bias, s1 = bias, s2 = bias, s3 = bias;
    const float* xr = xs + (w * 4) * DIM;
    #pragma unroll
    for (int k = 0; k < DIM; ++k) {
        float wv = Ws[k * DIM + d];
        s0 = fmaf(xr[k], wv, s0);
        s1 = fmaf(xr[DIM + k], wv, s1);
        s2 = fmaf(xr[2 * DIM + k], wv, s2);
        s3 = fmaf(xr[3 * DIM + k], wv, s3);
    }
    _Float16* o = xmh + ((size_t)base + w * 4) * DIM + d;
    o[0] = (_Float16)s0;
    o[DIM] = (_Float16)s1;
    o[2 * DIM] = (_Float16)s2;
    o[3 * DIM] = (_Float16)s3;

    __syncthreads();                  // bases visible

    // ---- pass C (heavy): write records to base+rank (consecutive slots) ----
    if (heavy) {
        int ebase = bid * EPB;
        #pragma unroll
        for (int j = 0; j < 16; ++j) {
            unsigned u = rl[j];
            if (u != 0xFFFFFFFFu) {
                int e = ebase + j * 256 + tid;
                int esrc  = eidx[e];            // L2-hot re-read
                float ea  = eattr[e];
                unsigned bin  = (u >> 12) & 0x3FFu;
                unsigned slot = hb[bin] + (u & 0xFFFu);
                if (slot < SEGCAP)
                    rec[(size_t)(seg * NBIN + bin) * SEGCAP + slot] =
                        make_int2((esrc << 6) | (int)(u >> 22),
                                  __float_as_int(ea));
            }
        }
    }
}

// K2: one block per half-bin (1564 blocks, 32 nodes each) — r5 verbatim.
// Records land directly in per-node LDS lists; 8-lane group per node runs the
// online-softmax walk. Math identical to reference: running max exact;
// max-agg commutes with uniform positive rescale; eps 1/(denom+1e-16).
__global__ __launch_bounds__(256) void k_aggregate(const half8* __restrict__ xm8,
                                                   const int2* __restrict__ rec,
                                                   const unsigned* __restrict__ tails,
                                                   const float4* __restrict__ W_edge4,
                                                   const float4* __restrict__ att4,
                                                   const float4* __restrict__ x4,
                                                   float4* __restrict__ out4) {
    __shared__ int2 lst[32 * LMAX];               // 16 KB per-node record lists
    __shared__ unsigned degs[32];
    __shared__ unsigned scnt[SEGS];
    int tid  = threadIdx.x;
    int bin  = blockIdx.x >> 1;
    int half = blockIdx.x & 1;

    if (tid < SEGS) {
        unsigned c = tails[tid * NBIN + bin];
        scnt[tid] = c > SEGCAP ? SEGCAP : c;
    }
    if (tid < 32) degs[tid] = 0;
    __syncthreads();

    // scan the bin's 8 segments; keep records for this half's 32 nodes
    for (int s = 0; s < SEGS * SEGCAP; s += 256) {
        int slot = s + tid;
        int sg = slot / SEGCAP, i = slot % SEGCAP;
        if ((unsigned)i < scnt[sg]) {
            int2 r = rec[(size_t)(sg * NBIN + bin) * SEGCAP + i];
            unsigned nr = (unsigned)r.x & 63u;
            if ((int)(nr >> 5) == half) {
                unsigned k = atomicAdd(&degs[nr & 31u], 1u);
                if (k < LMAX) lst[(nr & 31u) * LMAX + k] = r;
            }
        }
    }
    __syncthreads();

    int lane = tid & 63;
    int wvi  = tid >> 6;
    int g = lane >> 3, t = lane & 7;
    int rr = wvi * 8 + g;
    int node = bin * 64 + half * 32 + rr;
    if (node >= N_NODES) return;

    unsigned deg = degs[rr];
    if (deg > LMAX) deg = LMAX;
    size_t obase = (size_t)node * 16 + 2 * t;
    if (deg == 0) {
        out4[obase] = x4[obase];
        out4[obase + 1] = x4[obase + 1];
        return;
    }
    float4 wa = W_edge4[2 * t], wb = W_edge4[2 * t + 1];
    float4 aa = att4[2 * t],    ab = att4[2 * t + 1];
    float we[8] = {wa.x, wa.y, wa.z, wa.w, wb.x, wb.y, wb.z, wb.w};
    float at[8] = {aa.x, aa.y, aa.z, aa.w, ab.x, ab.y, ab.z, ab.w};

    const int2* L = lst + rr * LMAX;
    int2 r = L[0];
    float ea = __int_as_float(r.y);
    half8 h  = xm8[(size_t)((unsigned)r.x >> 6) * 8 + t];

    float m = NEG_INF, denom = 0.f;
    float v[8];
    #pragma unroll
    for (int k = 0; k < 8; ++k) v[k] = 0.f;

    unsigned i = 0;
    while (true) {
        bool more = (i + 1) < deg;                // group-uniform
        float ea2; half8 h2;
        if (more) {
            int2 r2 = L[i + 1];
            ea2 = __int_as_float(r2.y);
            h2  = xm8[(size_t)((unsigned)r2.x >> 6) * 8 + t];
        }
        float msg[8];
        float p = 0.f;
        #pragma unroll
        for (int k = 0; k < 8; ++k) {
            float f = (float)h[k];
            msg[k] = fmaf(ea, we[k], f);
            float lr = fmaxf(msg[k], NEG_SLOPE * msg[k]);   // leaky (slope<1)
            p = fmaf(lr, at[k], p);
        }
        p += __shfl_xor(p, 1, 64);
        p += __shfl_xor(p, 2, 64);
        p += __shfl_xor(p, 4, 64);                // group-uniform logit
        if (i == 0) {
            m = p; denom = 1.f;
            #pragma unroll
            for (int k = 0; k < 8; ++k) v[k] = msg[k];
        } else {
            float M  = fmaxf(m, p);
            float so = __expf(m - M);
            float sn = __expf(p - M);
            denom = fmaf(denom, so, sn);
            #pragma unroll
            for (int k = 0; k < 8; ++k)
                v[k] = fmaxf(v[k] * so, msg[k] * sn);
            m = M;
        }
        if (!more) break;
        ea = ea2; h = h2; ++i;
    }
    float inv = 1.0f / (denom + 1e-16f);
    float4 xa = x4[obase], xb = x4[obase + 1];
    float4 r0, r1;
    r0.x = fmaf(v[0], inv, xa.x);
    r0.y = fmaf(v[1], inv, xa.y);
    r0.z = fmaf(v[2], inv, xa.z);
    r0.w = fmaf(v[3], inv, xa.w);
    r1.x = fmaf(v[4], inv, xb.x);
    r1.y = fmaf(v[5], inv, xb.y);
    r1.z = fmaf(v[6], inv, xb.z);
    r1.w = fmaf(v[7], inv, xb.w);
    out4[obase] = r0;
    out4[obase + 1] = r1;
}

extern "C" void kernel_launch(void* const* d_in, const int* in_sizes, int n_in,
                              void* d_out, int out_size, void* d_ws, size_t ws_size,
                              hipStream_t stream) {
    const float* x      = (const float*)d_in[0];
    const int*   eidx   = (const int*)d_in[1];     // [2, E] int32
    const float* eattr  = (const float*)d_in[2];
    const float* W_msg  = (const float*)d_in[3];
    const float* b_msg  = (const float*)d_in[4];
    const float* W_edge = (const float*)d_in[5];   // [1, D]
    const float* b_edge = (const float*)d_in[6];
    const float* att    = (const float*)d_in[7];
    float* out = (float*)d_out;

    // Workspace layout (~26 MB of 256 MiB):
    //   xmh:   N*64 fp16                    6.4 MB
    //   rec:   8*782*384 int2              19.2 MB ([seg][bin] slabs)
    //   tails: 8*782 u32                    25 KB  -- zeroed
    _Float16* xmh   = (_Float16*)d_ws;
    int2*     rec   = (int2*)(xmh + (size_t)N_NODES * DIM);
    unsigned* tails = (unsigned*)(rec + (size_t)SEGS * NBIN * SEGCAP);

    hipMemsetAsync(tails, 0, (size_t)SEGS * NBIN * 4, stream);

    k_pre<<<NB, 256, 0, stream>>>(x, W_msg, b_msg, b_edge, xmh,
                                  eidx, eattr, tails, rec);
    k_aggregate<<<NBIN * 2, 256, 0, stream>>>(
        (const half8*)xmh, rec, tails, (const float4*)W_edge,
        (const float4*)att, (const float4*)x, (float4*)out);
}